// Round 3
// baseline (424.606 us; speedup 1.0000x reference)
//
#include <hip/hip_runtime.h>
#include <math.h>

#define BB 512
#define SS 100
#define DE 150
#define DM 300   // 2*D_E (also == D_IN)
#define LL 101
#define NH 2

// ---- ws layout (float offsets) ----  total ~3.1 MB
#define WS_CLS    0        // [300]
#define WS_QK     960      // [2][300]
#define WS_S0     1600     // [2]
#define WS_CPOS   1604     // [100][2]
#define WS_CVEC   1804     // [300]
#define WS_COLSUM 2104     // [300]
#define WS_CST0   2404     // [2]
#define WS_STATS  2416     // [0]=a1 [1]=beta1 [2]=a2 [3]=beta2 [4,5]=out consts
#define WS_PART1  2432     // [64][2]
#define WS_PART2  2560     // [64][2]
#define WS_G      2688     // [1200][2]
#define WS_ZBAR   5120                      // [2][512][300]
#define WS_MSA    (WS_ZBAR + 2*512*300)     // [512][600]
#define WS_Y1     (WS_MSA + 512*600)        // [512][300]

// ---------------- k0a: attention constants ----------------
__global__ void k0a(const float* __restrict__ pos, const float* __restrict__ cle,
                    const float* __restrict__ Wq, const float* __restrict__ Wk,
                    const float* __restrict__ Wp1, const float* __restrict__ bp1,
                    float* __restrict__ ws) {
  __shared__ float cls[DM];
  __shared__ float q0[NH][DM];
  __shared__ float qk[NH][DM];
  int tid = threadIdx.x;
  for (int i = tid; i < DM; i += 256)
    cls[i] = (i < DE) ? cle[i] : pos[i - DE];   // pos_table row 0
  __syncthreads();
  // Q0[h][e] = sum_d cls[d]*Wq[h][d][e]
  for (int i = tid; i < NH * DM; i += 256) {
    int h = i / DM, e = i % DM;
    const float* w = Wq + h * DM * DM + e;
    float acc = 0.f;
    for (int d = 0; d < DM; ++d) acc += cls[d] * w[d * DM];
    q0[h][e] = acc;
  }
  __syncthreads();
  // qk[h][d] = sum_e Wk[h][d][e]*Q0[h][e]
  for (int i = tid; i < NH * DM; i += 256) {
    int h = i / DM, d = i % DM;
    const float* w = Wk + h * DM * DM + d * DM;
    float acc = 0.f;
    for (int e = 0; e < DM; ++e) acc += w[e] * q0[h][e];
    qk[h][d] = acc;
    ws[WS_QK + i] = acc;
  }
  __syncthreads();
  if (tid < NH) {
    float acc = 0.f;
    for (int d = 0; d < DM; ++d) acc += cls[d] * qk[tid][d];
    ws[WS_S0 + tid] = acc;
  }
  for (int i = tid; i < DM; i += 256) ws[WS_CLS + i] = cls[i];
  // cpos[tt][h] = pos_table[tt+1] . qk[h][150:300]
  for (int i = tid; i < SS * NH; i += 256) {
    int tt = i / NH, h = i % NH;
    const float* pr = pos + (tt + 1) * DE;
    float acc = 0.f;
    for (int j = 0; j < DE; ++j) acc += pr[j] * qk[h][DE + j];
    ws[WS_CPOS + i] = acc;
  }
  // cvec[n] = bp1[n] + sum_j cls[j]*Wp1[600+j][n];  colsum[n] = sum_{k<600} Wp1[k][n]
  for (int n = tid; n < DM; n += 256) {
    float cv = bp1[n], cs = 0.f;
    for (int k = 0; k < 600; ++k) cs += Wp1[k * 300 + n];
    for (int j = 0; j < 300; ++j) cv += cls[j] * Wp1[(600 + j) * 300 + n];
    ws[WS_CVEC + n] = cv;
    ws[WS_COLSUM + n] = cs;
  }
}

// ---------------- k0b: G = fc1_W @ fc2_W ----------------
__global__ void k0b(const float* __restrict__ f1W, const float* __restrict__ f2W,
                    const float* __restrict__ f1b, const float* __restrict__ f2b,
                    float* __restrict__ ws) {
  int t = blockIdx.x * 256 + threadIdx.x;
  if (t < 2400) {
    int k = t >> 1, c = t & 1;
    const float* r = f1W + k * 512;
    float acc = 0.f;
    for (int m = 0; m < 512; ++m) acc += r[m] * f2W[m * 2 + c];
    ws[WS_G + t] = acc;
  } else if (t < 2402) {
    int c = t - 2400;
    float acc = f2b[c];
    for (int m = 0; m < 512; ++m) acc += f1b[m] * f2W[m * 2 + c];
    ws[WS_CST0 + c] = acc;
  }
}

// ---------------- kA: per-batch fused h-GEMM -> scores -> softmax -> zbar ----------------
// LDS: hb 100x151 = 60,400 B  +  aux 1200 floats = 4,800 B  -> 65,200 B <= 64 KiB limit.
// aux phase 1: staged Wp k-slice [8][150].
// aux phase 2+: [0..299]=qk[h][0:150], [300..599]=cls, [600..801]=scores, [802..1003]=softmax p.
__launch_bounds__(256)
__global__ void kA(const float* __restrict__ x, const float* __restrict__ Wp,
                   const float* __restrict__ bp, const float* __restrict__ pos,
                   float* __restrict__ ws) {
  __shared__ float hb[SS][DE + 1];
  __shared__ float aux[1200];
  int b = blockIdx.x, tid = threadIdx.x;
  int tx = tid & 15, ty = tid >> 4;

  // ---- phase 1: h[b] = relu(x[b] @ Wp + bp) ----
  float acc[7][10];
#pragma unroll
  for (int i = 0; i < 7; ++i)
#pragma unroll
    for (int j = 0; j < 10; ++j) acc[i][j] = 0.f;
  const float* xb = x + b * SS * DM;

  for (int kc = 0; kc < 296; kc += 8) {
    for (int i = tid; i < 8 * DE; i += 256)
      aux[i] = Wp[(kc + i / DE) * DE + (i % DE)];
    __syncthreads();
    float a[7][8];
#pragma unroll
    for (int i = 0; i < 7; ++i) {
      int r = ty + 16 * i; if (r > SS - 1) r = SS - 1;
      const float* xr = xb + r * DM + kc;
      float4 q0 = *(const float4*)xr;
      float4 q1 = *(const float4*)(xr + 4);
      a[i][0] = q0.x; a[i][1] = q0.y; a[i][2] = q0.z; a[i][3] = q0.w;
      a[i][4] = q1.x; a[i][5] = q1.y; a[i][6] = q1.z; a[i][7] = q1.w;
    }
#pragma unroll
    for (int kk = 0; kk < 8; ++kk) {
      float bv[10];
#pragma unroll
      for (int j = 0; j < 10; ++j) {
        int c = tx * 10 + j;
        bv[j] = (c < DE) ? aux[kk * DE + c] : 0.f;
      }
#pragma unroll
      for (int i = 0; i < 7; ++i)
#pragma unroll
        for (int j = 0; j < 10; ++j) acc[i][j] += a[i][kk] * bv[j];
    }
    __syncthreads();
  }
  { // tail: kc = 296, width 4
    const int kc = 296;
    for (int i = tid; i < 4 * DE; i += 256)
      aux[i] = Wp[(kc + i / DE) * DE + (i % DE)];
    __syncthreads();
    float a[7][4];
#pragma unroll
    for (int i = 0; i < 7; ++i) {
      int r = ty + 16 * i; if (r > SS - 1) r = SS - 1;
      const float* xr = xb + r * DM + kc;
      float4 q0 = *(const float4*)xr;
      a[i][0] = q0.x; a[i][1] = q0.y; a[i][2] = q0.z; a[i][3] = q0.w;
    }
#pragma unroll
    for (int kk = 0; kk < 4; ++kk) {
      float bv[10];
#pragma unroll
      for (int j = 0; j < 10; ++j) {
        int c = tx * 10 + j;
        bv[j] = (c < DE) ? aux[kk * DE + c] : 0.f;
      }
#pragma unroll
      for (int i = 0; i < 7; ++i)
#pragma unroll
        for (int j = 0; j < 10; ++j) acc[i][j] += a[i][kk] * bv[j];
    }
    __syncthreads();
  }
#pragma unroll
  for (int i = 0; i < 7; ++i) {
    int r = ty + 16 * i;
    if (r < SS) {
#pragma unroll
      for (int j = 0; j < 10; ++j) {
        int c = tx * 10 + j;
        if (c < DE) {
          float v = acc[i][j] + bp[c];
          hb[r][c] = v > 0.f ? v : 0.f;
        }
      }
    }
  }
  // reload aux: qk halves + cls
  for (int i = tid; i < DM; i += 256) {
    aux[i] = ws[WS_QK + (i / DE) * DM + (i % DE)];
    aux[DM + i] = ws[WS_CLS + i];
  }
  __syncthreads();

  // ---- phase 2: scores ----
  if (tid < NH * SS) {
    int hh = tid / SS, tt = tid % SS;
    float s = 0.f;
    for (int j = 0; j < DE; ++j) s += hb[tt][j] * aux[hh * DE + j];
    aux[600 + hh * LL + tt + 1] = s + ws[WS_CPOS + tt * NH + hh];
  } else if (tid < NH * SS + NH) {
    int hh = tid - NH * SS;
    aux[600 + hh * LL] = ws[WS_S0 + hh];
  }
  __syncthreads();

  // ---- phase 3: softmax (one wave per head) ----
  int wave = tid >> 6, lane = tid & 63;
  if (wave < NH) {
    float v0 = aux[600 + wave * LL + lane];
    float v1 = (lane + 64 < LL) ? aux[600 + wave * LL + lane + 64] : -1e30f;
    float m = fmaxf(v0, v1);
    for (int o = 32; o; o >>= 1) m = fmaxf(m, __shfl_xor(m, o));
    float e0 = expf(v0 - m);
    float e1 = (lane + 64 < LL) ? expf(v1 - m) : 0.f;
    float s = e0 + e1;
    for (int o = 32; o; o >>= 1) s += __shfl_xor(s, o);
    float inv = 1.f / s;
    aux[802 + wave * LL + lane] = e0 * inv;
    if (lane + 64 < LL) aux[802 + wave * LL + lane + 64] = e1 * inv;
  }
  __syncthreads();

  // ---- phase 4: zbar[h][d] = sum_t p[t]*z[b,t,d] ----
  for (int o = tid; o < NH * DM; o += 256) {
    int hh = o / DM, d = o % DM;
    const float* p = &aux[802 + hh * LL];
    float acc2 = p[0] * aux[DM + d];
    if (d < DE) {
      for (int t = 1; t <= SS; ++t) acc2 += p[t] * hb[t - 1][d];
    } else {
      int dd = d - DE;
      for (int t = 1; t <= SS; ++t) acc2 += p[t] * pos[t * DE + dd];
    }
    ws[WS_ZBAR + hh * (BB * DM) + b * DM + d] = acc2;
  }
}

// ---------------- k3: msa0 = zbar @ Wv (per head) ----------------
__launch_bounds__(256)
__global__ void k3(const float* __restrict__ Wv, float* __restrict__ ws) {
  __shared__ float zb[8][DM];
  int blk = blockIdx.x;            // 128 = 2 heads x 64 tiles
  int hh = blk >> 6, b0 = (blk & 63) * 8;
  int tid = threadIdx.x;
  const float* z = ws + WS_ZBAR + hh * BB * DM + b0 * DM;
  for (int i = tid; i < 8 * DM; i += 256) zb[i / DM][i % DM] = z[i];
  __syncthreads();
  const float* wv = Wv + hh * DM * DM;
  for (int e = tid; e < DM; e += 256) {
    float acc[8] = {0.f, 0.f, 0.f, 0.f, 0.f, 0.f, 0.f, 0.f};
    for (int d = 0; d < DM; ++d) {
      float w = wv[d * DM + e];
#pragma unroll
      for (int i = 0; i < 8; ++i) acc[i] += zb[i][d] * w;
    }
#pragma unroll
    for (int i = 0; i < 8; ++i)
      ws[WS_MSA + (b0 + i) * 600 + hh * DM + e] = acc[i];
  }
}

// ---------------- k4a/k4b: bn1 channel-0 stats ----------------
__global__ void k4a(float* __restrict__ ws) {
  int tid = threadIdx.x, bid = blockIdx.x;
  float s = 0.f, ss = 0.f;
  for (int i = bid * 256 + tid; i < BB * 600; i += 64 * 256) {
    float v = ws[WS_MSA + i];
    s += v; ss += v * v;
  }
  for (int o = 32; o; o >>= 1) { s += __shfl_xor(s, o); ss += __shfl_xor(ss, o); }
  __shared__ float sh[2][4];
  int wave = tid >> 6, lane = tid & 63;
  if (!lane) { sh[0][wave] = s; sh[1][wave] = ss; }
  __syncthreads();
  if (!tid) {
    float S = 0.f, SS2 = 0.f;
    for (int w = 0; w < 4; ++w) { S += sh[0][w]; SS2 += sh[1][w]; }
    ws[WS_PART1 + bid * 2] = S;
    ws[WS_PART1 + bid * 2 + 1] = SS2;
  }
}
__global__ void k4b(const float* __restrict__ g, const float* __restrict__ bv,
                    float* __restrict__ ws) {
  int tid = threadIdx.x;
  float s = ws[WS_PART1 + tid * 2], ss = ws[WS_PART1 + tid * 2 + 1];
  for (int o = 32; o; o >>= 1) { s += __shfl_xor(s, o); ss += __shfl_xor(ss, o); }
  if (!tid) {
    float n = (float)(BB * 600);
    float mean = s / n, var = ss / n - mean * mean;
    float a = (1.f / sqrtf(var + 1e-5f)) * g[0];
    ws[WS_STATS + 0] = a;
    ws[WS_STATS + 1] = bv[0] - a * mean;
  }
}

// ---------------- k5: y1 = relu(a1*(msa0@Wp1[:600]) + beta1*colsum + cvec) ----------------
__launch_bounds__(256)
__global__ void k5(const float* __restrict__ Wp1, float* __restrict__ ws) {
  __shared__ float ab[8][600];
  int b0 = blockIdx.x * 8, tid = threadIdx.x;
  for (int i = tid; i < 8 * 600; i += 256) ab[i / 600][i % 600] = ws[WS_MSA + b0 * 600 + i];
  __syncthreads();
  float a1 = ws[WS_STATS + 0], beta1 = ws[WS_STATS + 1];
  for (int n = tid; n < DM; n += 256) {
    float acc[8] = {0.f, 0.f, 0.f, 0.f, 0.f, 0.f, 0.f, 0.f};
    for (int k = 0; k < 600; ++k) {
      float w = Wp1[k * 300 + n];
#pragma unroll
      for (int i = 0; i < 8; ++i) acc[i] += ab[i][k] * w;
    }
    float c = beta1 * ws[WS_COLSUM + n] + ws[WS_CVEC + n];
#pragma unroll
    for (int i = 0; i < 8; ++i) {
      float v = a1 * acc[i] + c;
      ws[WS_Y1 + (b0 + i) * 300 + n] = v > 0.f ? v : 0.f;
    }
  }
}

// ---------------- k6a/k6b: bn2 channel-0 stats + final consts ----------------
__global__ void k6a(float* __restrict__ ws) {
  int tid = threadIdx.x, bid = blockIdx.x;
  float s = 0.f, ss = 0.f;
  for (int i = bid * 256 + tid; i < BB * 300; i += 64 * 256) {
    float v = ws[WS_Y1 + i];
    s += v; ss += v * v;
  }
  for (int o = 32; o; o >>= 1) { s += __shfl_xor(s, o); ss += __shfl_xor(ss, o); }
  __shared__ float sh[2][4];
  int wave = tid >> 6, lane = tid & 63;
  if (!lane) { sh[0][wave] = s; sh[1][wave] = ss; }
  __syncthreads();
  if (!tid) {
    float S = 0.f, SS2 = 0.f;
    for (int w = 0; w < 4; ++w) { S += sh[0][w]; SS2 += sh[1][w]; }
    ws[WS_PART2 + bid * 2] = S;
    ws[WS_PART2 + bid * 2 + 1] = SS2;
  }
}
__global__ void k6b(const float* __restrict__ g2, const float* __restrict__ b2,
                    float* __restrict__ ws) {
  int tid = threadIdx.x;
  float s = 0.f, ss = 0.f;
  if (tid < 64) { s = ws[WS_PART2 + tid * 2]; ss = ws[WS_PART2 + tid * 2 + 1]; }
  for (int o = 32; o; o >>= 1) { s += __shfl_xor(s, o); ss += __shfl_xor(ss, o); }
  __shared__ float b2sh;
  if (tid == 0) {
    float n = (float)(BB * 300);
    float mean = s / n, var = ss / n - mean * mean;
    float a = (1.f / sqrtf(var + 1e-5f)) * g2[0];
    b2sh = b2[0] - a * mean;
    ws[WS_STATS + 2] = a; ws[WS_STATS + 3] = b2sh;
  }
  __syncthreads();
  if (tid < 2) {
    int c = tid;
    float sg1 = 0.f, sg2 = 0.f, sg3 = 0.f;
    for (int k = 0; k < 300; ++k) sg1 += ws[WS_G + k * 2 + c];
    for (int k = 300; k < 900; ++k) sg2 += ws[WS_G + k * 2 + c];
    for (int j = 0; j < 300; ++j) sg3 += ws[WS_CLS + j] * ws[WS_G + (900 + j) * 2 + c];
    ws[WS_STATS + 4 + c] = ws[WS_CST0 + c] + sg3 + b2sh * sg1 + ws[WS_STATS + 1] * sg2;
  }
}

// ---------------- k7: out = a2*(y1@G1) + a1*(msa0@G2) + const ----------------
__global__ void k7(float* __restrict__ out, const float* __restrict__ ws) {
  __shared__ float Gs[1800];
  int tid = threadIdx.x;
  for (int i = tid; i < 1800; i += 256) Gs[i] = ws[WS_G + i];
  __syncthreads();
  int b = blockIdx.x * 256 + tid;
  float a1 = ws[WS_STATS + 0], a2 = ws[WS_STATS + 2];
  float c0 = ws[WS_STATS + 4], c1 = ws[WS_STATS + 5];
  const float* y1 = ws + WS_Y1 + b * 300;
  const float* ms = ws + WS_MSA + b * 600;
  float o0 = 0.f, o1 = 0.f;
  for (int k = 0; k < 300; ++k) { float v = y1[k]; o0 += v * Gs[k * 2]; o1 += v * Gs[k * 2 + 1]; }
  float p0 = 0.f, p1 = 0.f;
  for (int j = 0; j < 600; ++j) { float v = ms[j]; p0 += v * Gs[(300 + j) * 2]; p1 += v * Gs[(300 + j) * 2 + 1]; }
  out[b * 2] = a2 * o0 + a1 * p0 + c0;
  out[b * 2 + 1] = a2 * o1 + a1 * p1 + c1;
}

extern "C" void kernel_launch(void* const* d_in, const int* in_sizes, int n_in,
                              void* d_out, int out_size, void* d_ws, size_t ws_size,
                              hipStream_t stream) {
  const float* x    = (const float*)d_in[0];
  const float* Wp   = (const float*)d_in[1];
  const float* bp   = (const float*)d_in[2];
  const float* pos  = (const float*)d_in[3];
  const float* cle  = (const float*)d_in[4];
  const float* Wq   = (const float*)d_in[5];
  const float* Wk   = (const float*)d_in[6];
  const float* Wv   = (const float*)d_in[7];
  const float* bn1g = (const float*)d_in[8];
  const float* bn1b = (const float*)d_in[9];
  const float* Wp1  = (const float*)d_in[10];
  const float* bp1  = (const float*)d_in[11];
  const float* bn2g = (const float*)d_in[12];
  const float* bn2b = (const float*)d_in[13];
  const float* f1W  = (const float*)d_in[14];
  const float* f1b  = (const float*)d_in[15];
  const float* f2W  = (const float*)d_in[16];
  const float* f2b  = (const float*)d_in[17];
  float* ws = (float*)d_ws;
  float* out = (float*)d_out;

  hipLaunchKernelGGL(k0a, dim3(1), dim3(256), 0, stream, pos, cle, Wq, Wk, Wp1, bp1, ws);
  hipLaunchKernelGGL(k0b, dim3(10), dim3(256), 0, stream, f1W, f2W, f1b, f2b, ws);
  hipLaunchKernelGGL(kA, dim3(512), dim3(256), 0, stream, x, Wp, bp, pos, ws);
  hipLaunchKernelGGL(k3, dim3(128), dim3(256), 0, stream, Wv, ws);
  hipLaunchKernelGGL(k4a, dim3(64), dim3(256), 0, stream, ws);
  hipLaunchKernelGGL(k4b, dim3(1), dim3(64), 0, stream, bn1g, bn1b, ws);
  hipLaunchKernelGGL(k5, dim3(64), dim3(256), 0, stream, Wp1, ws);
  hipLaunchKernelGGL(k6a, dim3(64), dim3(256), 0, stream, ws);
  hipLaunchKernelGGL(k6b, dim3(1), dim3(256), 0, stream, bn2g, bn2b, ws);
  hipLaunchKernelGGL(k7, dim3(2), dim3(256), 0, stream, out, ws);
}

// Round 4
// 335.434 us; speedup vs baseline: 1.2658x; 1.2658x over previous
//
#include <hip/hip_runtime.h>
#include <hip/hip_fp16.h>
#include <math.h>

#define BB 512
#define SS 100
#define DE 150
#define DM 300   // 2*D_E (also == D_IN)
#define LL 101
#define NH 2

// ---- ws layout (float offsets) ----  total ~3.13 MB
#define WS_CLS    0        // [300]
#define WS_QK     320      // [2][300]
#define WS_S0     960      // [2]
#define WS_CPOS   964      // [100][2]
#define WS_CVEC   1200     // [300]
#define WS_COLSUM 1536     // [300]
#define WS_CST0   1856     // [2]
#define WS_STATS  1860     // [0]=a1 [1]=beta1 [2]=a2 [3]=beta2 [4,5]=out consts
#define WS_PART1  1920     // [64][2]
#define WS_PART2  2048     // [64][2]
#define WS_G      2176     // [1200][2]
#define WS_Q0     4608     // [2][300]
#define WS_P3     5248     // [15][2][300]
#define WS_ZBAR   14336                     // [2][512][300]
#define WS_MSA    (WS_ZBAR + 2*512*300)     // [512][600]
#define WS_Y1     (WS_MSA + 512*600)        // [512][300]

// ---------------- kC1: q0 | Wp1 partials | cls | G=fc1@fc2 ----------------
// grid 29: b<3 q0; 3<=b<18 Wp1 partials; b==18 cls; b>=19 G.
__global__ void kC1(const float* __restrict__ pos, const float* __restrict__ cle,
                    const float* __restrict__ Wq, const float* __restrict__ Wp1,
                    const float* __restrict__ f1W, const float* __restrict__ f2W,
                    const float* __restrict__ f1b, const float* __restrict__ f2b,
                    float* __restrict__ ws) {
  __shared__ float cls[DM];
  int b = blockIdx.x, tid = threadIdx.x;
  if (b < 18) {
    for (int i = tid; i < DM; i += 256) cls[i] = (i < DE) ? cle[i] : pos[i - DE];
    __syncthreads();
  }
  if (b < 3) {
    int idx = b * 256 + tid;
    if (idx < NH * DM) {
      int h = idx / DM, e = idx % DM;
      const float* w = Wq + h * DM * DM + e;
      float acc = 0.f;
      for (int d = 0; d < DM; ++d) acc += cls[d] * w[d * DM];
      ws[WS_Q0 + idx] = acc;
    }
  } else if (b < 18) {
    int kb = b - 3;
    for (int n = tid; n < DM; n += 256) {
      float cs = 0.f, cv = 0.f;
      for (int k = kb * 60; k < kb * 60 + 60; ++k) {
        float w = Wp1[k * 300 + n];
        if (k < 600) cs += w; else cv += cls[k - 600] * w;
      }
      ws[WS_P3 + kb * 600 + n] = cs;
      ws[WS_P3 + kb * 600 + 300 + n] = cv;
    }
  } else if (b == 18) {
    for (int i = tid; i < DM; i += 256)
      ws[WS_CLS + i] = (i < DE) ? cle[i] : pos[i - DE];
  } else {
    int t = (b - 19) * 256 + tid;
    if (t < 2400) {
      int k = t >> 1, c = t & 1;
      const float* r = f1W + k * 512;
      float acc = 0.f;
      for (int m = 0; m < 512; ++m) acc += r[m] * f2W[m * 2 + c];
      ws[WS_G + t] = acc;
    } else if (t < 2402) {
      int c = t - 2400;
      float acc = f2b[c];
      for (int m = 0; m < 512; ++m) acc += f1b[m] * f2W[m * 2 + c];
      ws[WS_CST0 + c] = acc;
    }
  }
}

// ---------------- kC2: qk[h][d] = Wk[h][d][:] . q0[h][:]  (wave per output) ----------------
__global__ void kC2(const float* __restrict__ Wk, float* __restrict__ ws) {
  __shared__ float q0s[NH * DM];
  int tid = threadIdx.x;
  for (int i = tid; i < NH * DM; i += 256) q0s[i] = ws[WS_Q0 + i];
  __syncthreads();
  int wave = tid >> 6, lane = tid & 63;
  int idx = blockIdx.x * 4 + wave;            // < 600
  int h = idx / DM, d = idx % DM;
  const float* w = Wk + h * DM * DM + d * DM;
  const float* q = q0s + h * DM;
  float acc = 0.f;
  for (int e = lane; e < DM; e += 64) acc += w[e] * q[e];
  for (int o = 32; o; o >>= 1) acc += __shfl_xor(acc, o);
  if (!lane) ws[WS_QK + idx] = acc;
}

// ---------------- kC3: cpos | s0 | combine(colsum,cvec) ----------------
// grid 52: b<50 cpos (wave per output); b==50 s0; b==51 combine.
__global__ void kC3(const float* __restrict__ pos, const float* __restrict__ bp1,
                    float* __restrict__ ws) {
  int b = blockIdx.x, tid = threadIdx.x;
  int wave = tid >> 6, lane = tid & 63;
  if (b < 50) {
    int idx = b * 4 + wave;                   // < 200, = tt*2+h
    int tt = idx >> 1, h = idx & 1;
    const float* pr = pos + (tt + 1) * DE;
    const float* qk = ws + WS_QK + h * DM + DE;
    float acc = 0.f;
    for (int j = lane; j < DE; j += 64) acc += pr[j] * qk[j];
    for (int o = 32; o; o >>= 1) acc += __shfl_xor(acc, o);
    if (!lane) ws[WS_CPOS + idx] = acc;
  } else if (b == 50) {
    if (wave < NH) {
      float acc = 0.f;
      for (int d = lane; d < DM; d += 64) acc += ws[WS_CLS + d] * ws[WS_QK + wave * DM + d];
      for (int o = 32; o; o >>= 1) acc += __shfl_xor(acc, o);
      if (!lane) ws[WS_S0 + wave] = acc;
    }
  } else {
    for (int n = tid; n < DM; n += 256) {
      float cs = 0.f, cv = bp1[n];
      for (int p = 0; p < 15; ++p) {
        cs += ws[WS_P3 + p * 600 + n];
        cv += ws[WS_P3 + p * 600 + 300 + n];
      }
      ws[WS_COLSUM + n] = cs;
      ws[WS_CVEC + n] = cv;
    }
  }
}

// ---------------- kA: per-batch fused h-GEMM -> scores -> softmax -> zbar ----------------
// LDS: hb fp16 100x152 = 30,400 B + aux 4,800 B = 35,200 B -> 4 blocks/CU.
__launch_bounds__(256)
__global__ void kA(const float* __restrict__ x, const float* __restrict__ Wp,
                   const float* __restrict__ bp, const float* __restrict__ pos,
                   float* __restrict__ ws) {
  __shared__ __half hb[SS][DE + 2];
  __shared__ float aux[1200];
  int b = blockIdx.x, tid = threadIdx.x;
  int tx = tid & 15, ty = tid >> 4;

  // ---- phase 1: h[b] = relu(x[b] @ Wp + bp) ----
  float acc[7][10];
#pragma unroll
  for (int i = 0; i < 7; ++i)
#pragma unroll
    for (int j = 0; j < 10; ++j) acc[i][j] = 0.f;
  const float* xb = x + b * SS * DM;

  for (int kc = 0; kc < 296; kc += 8) {
    for (int i = tid; i < 8 * DE; i += 256)
      aux[i] = Wp[(kc + i / DE) * DE + (i % DE)];
    __syncthreads();
    float a[7][8];
#pragma unroll
    for (int i = 0; i < 7; ++i) {
      int r = ty + 16 * i; if (r > SS - 1) r = SS - 1;
      const float* xr = xb + r * DM + kc;
      float4 q0 = *(const float4*)xr;
      float4 q1 = *(const float4*)(xr + 4);
      a[i][0] = q0.x; a[i][1] = q0.y; a[i][2] = q0.z; a[i][3] = q0.w;
      a[i][4] = q1.x; a[i][5] = q1.y; a[i][6] = q1.z; a[i][7] = q1.w;
    }
#pragma unroll
    for (int kk = 0; kk < 8; ++kk) {
      float bv[10];
#pragma unroll
      for (int j = 0; j < 10; ++j) {
        int c = tx * 10 + j;
        bv[j] = (c < DE) ? aux[kk * DE + c] : 0.f;
      }
#pragma unroll
      for (int i = 0; i < 7; ++i)
#pragma unroll
        for (int j = 0; j < 10; ++j) acc[i][j] += a[i][kk] * bv[j];
    }
    __syncthreads();
  }
  { // tail: kc = 296, width 4
    const int kc = 296;
    for (int i = tid; i < 4 * DE; i += 256)
      aux[i] = Wp[(kc + i / DE) * DE + (i % DE)];
    __syncthreads();
    float a[7][4];
#pragma unroll
    for (int i = 0; i < 7; ++i) {
      int r = ty + 16 * i; if (r > SS - 1) r = SS - 1;
      const float* xr = xb + r * DM + kc;
      float4 q0 = *(const float4*)xr;
      a[i][0] = q0.x; a[i][1] = q0.y; a[i][2] = q0.z; a[i][3] = q0.w;
    }
#pragma unroll
    for (int kk = 0; kk < 4; ++kk) {
      float bv[10];
#pragma unroll
      for (int j = 0; j < 10; ++j) {
        int c = tx * 10 + j;
        bv[j] = (c < DE) ? aux[kk * DE + c] : 0.f;
      }
#pragma unroll
      for (int i = 0; i < 7; ++i)
#pragma unroll
        for (int j = 0; j < 10; ++j) acc[i][j] += a[i][kk] * bv[j];
    }
    __syncthreads();
  }
#pragma unroll
  for (int i = 0; i < 7; ++i) {
    int r = ty + 16 * i;
    if (r < SS) {
#pragma unroll
      for (int j = 0; j < 10; ++j) {
        int c = tx * 10 + j;
        if (c < DE) {
          float v = acc[i][j] + bp[c];
          hb[r][c] = __float2half(v > 0.f ? v : 0.f);
        }
      }
    }
  }
  // reload aux: qk first-halves + cls
  for (int i = tid; i < DM; i += 256) {
    aux[i] = ws[WS_QK + (i / DE) * DM + (i % DE)];
    aux[DM + i] = ws[WS_CLS + i];
  }
  __syncthreads();

  // ---- phase 2: scores ----
  if (tid < NH * SS) {
    int hh = tid / SS, tt = tid % SS;
    float s = 0.f;
    for (int j = 0; j < DE; ++j) s += __half2float(hb[tt][j]) * aux[hh * DE + j];
    aux[600 + hh * LL + tt + 1] = s + ws[WS_CPOS + tt * NH + hh];
  } else if (tid < NH * SS + NH) {
    int hh = tid - NH * SS;
    aux[600 + hh * LL] = ws[WS_S0 + hh];
  }
  __syncthreads();

  // ---- phase 3: softmax (one wave per head) ----
  int wave = tid >> 6, lane = tid & 63;
  if (wave < NH) {
    float v0 = aux[600 + wave * LL + lane];
    float v1 = (lane + 64 < LL) ? aux[600 + wave * LL + lane + 64] : -1e30f;
    float m = fmaxf(v0, v1);
    for (int o = 32; o; o >>= 1) m = fmaxf(m, __shfl_xor(m, o));
    float e0 = expf(v0 - m);
    float e1 = (lane + 64 < LL) ? expf(v1 - m) : 0.f;
    float s = e0 + e1;
    for (int o = 32; o; o >>= 1) s += __shfl_xor(s, o);
    float inv = 1.f / s;
    aux[802 + wave * LL + lane] = e0 * inv;
    if (lane + 64 < LL) aux[802 + wave * LL + lane + 64] = e1 * inv;
  }
  __syncthreads();

  // ---- phase 4: zbar[h][d] = sum_t p[t]*z[b,t,d] ----
  for (int o = tid; o < NH * DM; o += 256) {
    int hh = o / DM, d = o % DM;
    const float* p = &aux[802 + hh * LL];
    float acc2 = p[0] * aux[DM + d];
    if (d < DE) {
      for (int t = 1; t <= SS; ++t) acc2 += p[t] * __half2float(hb[t - 1][d]);
    } else {
      int dd = d - DE;
      for (int t = 1; t <= SS; ++t) acc2 += p[t] * pos[t * DE + dd];
    }
    ws[WS_ZBAR + hh * (BB * DM) + b * DM + d] = acc2;
  }
}

// ---------------- k3: msa0 = zbar @ Wv (per head) ----------------
__launch_bounds__(256)
__global__ void k3(const float* __restrict__ Wv, float* __restrict__ ws) {
  __shared__ float zb[8][DM];
  int blk = blockIdx.x;            // 128 = 2 heads x 64 tiles
  int hh = blk >> 6, b0 = (blk & 63) * 8;
  int tid = threadIdx.x;
  const float* z = ws + WS_ZBAR + hh * BB * DM + b0 * DM;
  for (int i = tid; i < 8 * DM; i += 256) zb[i / DM][i % DM] = z[i];
  __syncthreads();
  const float* wv = Wv + hh * DM * DM;
  for (int e = tid; e < DM; e += 256) {
    float acc[8] = {0.f, 0.f, 0.f, 0.f, 0.f, 0.f, 0.f, 0.f};
    for (int d = 0; d < DM; ++d) {
      float w = wv[d * DM + e];
#pragma unroll
      for (int i = 0; i < 8; ++i) acc[i] += zb[i][d] * w;
    }
#pragma unroll
    for (int i = 0; i < 8; ++i)
      ws[WS_MSA + (b0 + i) * 600 + hh * DM + e] = acc[i];
  }
}

// ---------------- k4a/k4b: bn1 channel-0 stats ----------------
__global__ void k4a(float* __restrict__ ws) {
  int tid = threadIdx.x, bid = blockIdx.x;
  float s = 0.f, ss = 0.f;
  for (int i = bid * 256 + tid; i < BB * 600; i += 64 * 256) {
    float v = ws[WS_MSA + i];
    s += v; ss += v * v;
  }
  for (int o = 32; o; o >>= 1) { s += __shfl_xor(s, o); ss += __shfl_xor(ss, o); }
  __shared__ float sh[2][4];
  int wave = tid >> 6, lane = tid & 63;
  if (!lane) { sh[0][wave] = s; sh[1][wave] = ss; }
  __syncthreads();
  if (!tid) {
    float S = 0.f, SS2 = 0.f;
    for (int w = 0; w < 4; ++w) { S += sh[0][w]; SS2 += sh[1][w]; }
    ws[WS_PART1 + bid * 2] = S;
    ws[WS_PART1 + bid * 2 + 1] = SS2;
  }
}
__global__ void k4b(const float* __restrict__ g, const float* __restrict__ bv,
                    float* __restrict__ ws) {
  int tid = threadIdx.x;
  float s = ws[WS_PART1 + tid * 2], ss = ws[WS_PART1 + tid * 2 + 1];
  for (int o = 32; o; o >>= 1) { s += __shfl_xor(s, o); ss += __shfl_xor(ss, o); }
  if (!tid) {
    float n = (float)(BB * 600);
    float mean = s / n, var = ss / n - mean * mean;
    float a = (1.f / sqrtf(var + 1e-5f)) * g[0];
    ws[WS_STATS + 0] = a;
    ws[WS_STATS + 1] = bv[0] - a * mean;
  }
}

// ---------------- k5: y1 = relu(a1*(msa0@Wp1[:600]) + beta1*colsum + cvec) ----------------
__launch_bounds__(256)
__global__ void k5(const float* __restrict__ Wp1, float* __restrict__ ws) {
  __shared__ float ab[8][600];
  int b0 = blockIdx.x * 8, tid = threadIdx.x;
  for (int i = tid; i < 8 * 600; i += 256) ab[i / 600][i % 600] = ws[WS_MSA + b0 * 600 + i];
  __syncthreads();
  float a1 = ws[WS_STATS + 0], beta1 = ws[WS_STATS + 1];
  for (int n = tid; n < DM; n += 256) {
    float acc[8] = {0.f, 0.f, 0.f, 0.f, 0.f, 0.f, 0.f, 0.f};
    for (int k = 0; k < 600; ++k) {
      float w = Wp1[k * 300 + n];
#pragma unroll
      for (int i = 0; i < 8; ++i) acc[i] += ab[i][k] * w;
    }
    float c = beta1 * ws[WS_COLSUM + n] + ws[WS_CVEC + n];
#pragma unroll
    for (int i = 0; i < 8; ++i) {
      float v = a1 * acc[i] + c;
      ws[WS_Y1 + (b0 + i) * 300 + n] = v > 0.f ? v : 0.f;
    }
  }
}

// ---------------- k6a/k6b: bn2 channel-0 stats + final consts ----------------
__global__ void k6a(float* __restrict__ ws) {
  int tid = threadIdx.x, bid = blockIdx.x;
  float s = 0.f, ss = 0.f;
  for (int i = bid * 256 + tid; i < BB * 300; i += 64 * 256) {
    float v = ws[WS_Y1 + i];
    s += v; ss += v * v;
  }
  for (int o = 32; o; o >>= 1) { s += __shfl_xor(s, o); ss += __shfl_xor(ss, o); }
  __shared__ float sh[2][4];
  int wave = tid >> 6, lane = tid & 63;
  if (!lane) { sh[0][wave] = s; sh[1][wave] = ss; }
  __syncthreads();
  if (!tid) {
    float S = 0.f, SS2 = 0.f;
    for (int w = 0; w < 4; ++w) { S += sh[0][w]; SS2 += sh[1][w]; }
    ws[WS_PART2 + bid * 2] = S;
    ws[WS_PART2 + bid * 2 + 1] = SS2;
  }
}
__global__ void k6b(const float* __restrict__ g2, const float* __restrict__ b2,
                    float* __restrict__ ws) {
  int tid = threadIdx.x;
  float s = 0.f, ss = 0.f;
  if (tid < 64) { s = ws[WS_PART2 + tid * 2]; ss = ws[WS_PART2 + tid * 2 + 1]; }
  for (int o = 32; o; o >>= 1) { s += __shfl_xor(s, o); ss += __shfl_xor(ss, o); }
  __shared__ float b2sh;
  if (tid == 0) {
    float n = (float)(BB * 300);
    float mean = s / n, var = ss / n - mean * mean;
    float a = (1.f / sqrtf(var + 1e-5f)) * g2[0];
    b2sh = b2[0] - a * mean;
    ws[WS_STATS + 2] = a; ws[WS_STATS + 3] = b2sh;
  }
  __syncthreads();
  if (tid < 2) {
    int c = tid;
    float sg1 = 0.f, sg2 = 0.f, sg3 = 0.f;
    for (int k = 0; k < 300; ++k) sg1 += ws[WS_G + k * 2 + c];
    for (int k = 300; k < 900; ++k) sg2 += ws[WS_G + k * 2 + c];
    for (int j = 0; j < 300; ++j) sg3 += ws[WS_CLS + j] * ws[WS_G + (900 + j) * 2 + c];
    ws[WS_STATS + 4 + c] = ws[WS_CST0 + c] + sg3 + b2sh * sg1 + ws[WS_STATS + 1] * sg2;
  }
}

// ---------------- k7: out = a2*(y1@G1) + a1*(msa0@G2) + const ----------------
__global__ void k7(float* __restrict__ out, const float* __restrict__ ws) {
  __shared__ float Gs[1800];
  int tid = threadIdx.x;
  for (int i = tid; i < 1800; i += 64) Gs[i] = ws[WS_G + i];
  __syncthreads();
  int b = blockIdx.x * 64 + tid;
  float a1 = ws[WS_STATS + 0], a2 = ws[WS_STATS + 2];
  float c0 = ws[WS_STATS + 4], c1 = ws[WS_STATS + 5];
  const float* y1 = ws + WS_Y1 + b * 300;
  const float* ms = ws + WS_MSA + b * 600;
  float o0 = 0.f, o1 = 0.f;
  for (int k = 0; k < 300; ++k) { float v = y1[k]; o0 += v * Gs[k * 2]; o1 += v * Gs[k * 2 + 1]; }
  float p0 = 0.f, p1 = 0.f;
  for (int j = 0; j < 600; ++j) { float v = ms[j]; p0 += v * Gs[(300 + j) * 2]; p1 += v * Gs[(300 + j) * 2 + 1]; }
  out[b * 2] = a2 * o0 + a1 * p0 + c0;
  out[b * 2 + 1] = a2 * o1 + a1 * p1 + c1;
}

extern "C" void kernel_launch(void* const* d_in, const int* in_sizes, int n_in,
                              void* d_out, int out_size, void* d_ws, size_t ws_size,
                              hipStream_t stream) {
  const float* x    = (const float*)d_in[0];
  const float* Wp   = (const float*)d_in[1];
  const float* bp   = (const float*)d_in[2];
  const float* pos  = (const float*)d_in[3];
  const float* cle  = (const float*)d_in[4];
  const float* Wq   = (const float*)d_in[5];
  const float* Wk   = (const float*)d_in[6];
  const float* Wv   = (const float*)d_in[7];
  const float* bn1g = (const float*)d_in[8];
  const float* bn1b = (const float*)d_in[9];
  const float* Wp1  = (const float*)d_in[10];
  const float* bp1  = (const float*)d_in[11];
  const float* bn2g = (const float*)d_in[12];
  const float* bn2b = (const float*)d_in[13];
  const float* f1W  = (const float*)d_in[14];
  const float* f1b  = (const float*)d_in[15];
  const float* f2W  = (const float*)d_in[16];
  const float* f2b  = (const float*)d_in[17];
  float* ws = (float*)d_ws;
  float* out = (float*)d_out;

  hipLaunchKernelGGL(kC1, dim3(29), dim3(256), 0, stream, pos, cle, Wq, Wp1, f1W, f2W, f1b, f2b, ws);
  hipLaunchKernelGGL(kC2, dim3(150), dim3(256), 0, stream, Wk, ws);
  hipLaunchKernelGGL(kC3, dim3(52), dim3(256), 0, stream, pos, bp1, ws);
  hipLaunchKernelGGL(kA, dim3(512), dim3(256), 0, stream, x, Wp, bp, pos, ws);
  hipLaunchKernelGGL(k3, dim3(128), dim3(256), 0, stream, Wv, ws);
  hipLaunchKernelGGL(k4a, dim3(64), dim3(256), 0, stream, ws);
  hipLaunchKernelGGL(k4b, dim3(1), dim3(64), 0, stream, bn1g, bn1b, ws);
  hipLaunchKernelGGL(k5, dim3(64), dim3(256), 0, stream, Wp1, ws);
  hipLaunchKernelGGL(k6a, dim3(64), dim3(256), 0, stream, ws);
  hipLaunchKernelGGL(k6b, dim3(1), dim3(256), 0, stream, bn2g, bn2b, ws);
  hipLaunchKernelGGL(k7, dim3(8), dim3(64), 0, stream, out, ws);
}

// Round 6
// 252.730 us; speedup vs baseline: 1.6801x; 1.3272x over previous
//
#include <hip/hip_runtime.h>
#include <hip/hip_fp16.h>
#include <math.h>

#define BB 512
#define SS 100
#define DE 150
#define DM 300   // 2*D_E (also == D_IN)
#define LL 101
#define NH 2

// ---- ws layout (float offsets) ----
#define WS_CLS    0        // [300]
#define WS_QK     320      // [2][300]
#define WS_S0     960      // [2]
#define WS_CPOS   964      // [100][2]
#define WS_CVEC   1200     // [300]
#define WS_COLSUM 1536     // [300]
#define WS_CST0   1856     // [2]
#define WS_STATS  1860     // [0]=a1 [1]=beta1
#define WS_PART1  1920     // [64][2]
#define WS_PART2  2048     // [64][2]
#define WS_G      2176     // [1200][2]
#define WS_Q0     4608     // [2][300]
#define WS_P3     5248     // [15][2][300]
#define WS_MSA    14336                     // [512][600]
#define WS_Y1     (WS_MSA + 512*600)        // [512][300]

// ---------------- kC1: q0 | Wp1 partials | cls | G=fc1@fc2 ----------------
__global__ void kC1(const float* __restrict__ pos, const float* __restrict__ cle,
                    const float* __restrict__ Wq, const float* __restrict__ Wp1,
                    const float* __restrict__ f1W, const float* __restrict__ f2W,
                    const float* __restrict__ f1b, const float* __restrict__ f2b,
                    float* __restrict__ ws) {
  __shared__ float cls[DM];
  int b = blockIdx.x, tid = threadIdx.x;
  if (b < 18) {
    for (int i = tid; i < DM; i += 256) cls[i] = (i < DE) ? cle[i] : pos[i - DE];
    __syncthreads();
  }
  if (b < 3) {
    int idx = b * 256 + tid;
    if (idx < NH * DM) {
      int h = idx / DM, e = idx % DM;
      const float* w = Wq + h * DM * DM + e;
      float acc = 0.f;
      for (int d = 0; d < DM; ++d) acc += cls[d] * w[d * DM];
      ws[WS_Q0 + idx] = acc;
    }
  } else if (b < 18) {
    int kb = b - 3;
    for (int n = tid; n < DM; n += 256) {
      float cs = 0.f, cv = 0.f;
      for (int k = kb * 60; k < kb * 60 + 60; ++k) {
        float w = Wp1[k * 300 + n];
        if (k < 600) cs += w; else cv += cls[k - 600] * w;
      }
      ws[WS_P3 + kb * 600 + n] = cs;
      ws[WS_P3 + kb * 600 + 300 + n] = cv;
    }
  } else if (b == 18) {
    for (int i = tid; i < DM; i += 256)
      ws[WS_CLS + i] = (i < DE) ? cle[i] : pos[i - DE];
  } else {
    int t = (b - 19) * 256 + tid;
    if (t < 2400) {
      int k = t >> 1, c = t & 1;
      const float* r = f1W + k * 512;
      float acc = 0.f;
      for (int m = 0; m < 512; ++m) acc += r[m] * f2W[m * 2 + c];
      ws[WS_G + t] = acc;
    } else if (t < 2402) {
      int c = t - 2400;
      float acc = f2b[c];
      for (int m = 0; m < 512; ++m) acc += f1b[m] * f2W[m * 2 + c];
      ws[WS_CST0 + c] = acc;
    }
  }
}

// ---------------- kC2: qk[h][d] = Wk[h][d][:] . q0[h][:] (wave per output) ----------------
__global__ void kC2(const float* __restrict__ Wk, float* __restrict__ ws) {
  __shared__ float q0s[NH * DM];
  int tid = threadIdx.x;
  for (int i = tid; i < NH * DM; i += 256) q0s[i] = ws[WS_Q0 + i];
  __syncthreads();
  int wave = tid >> 6, lane = tid & 63;
  int idx = blockIdx.x * 4 + wave;            // < 600
  int h = idx / DM, d = idx % DM;
  const float* w = Wk + h * DM * DM + d * DM;
  const float* q = q0s + h * DM;
  float acc = 0.f;
  for (int e = lane; e < DM; e += 64) acc += w[e] * q[e];
  for (int o = 32; o; o >>= 1) acc += __shfl_xor(acc, o);
  if (!lane) ws[WS_QK + idx] = acc;
}

// ---------------- kC3: cpos | s0 | combine(colsum,cvec) ----------------
__global__ void kC3(const float* __restrict__ pos, const float* __restrict__ bp1,
                    float* __restrict__ ws) {
  int b = blockIdx.x, tid = threadIdx.x;
  int wave = tid >> 6, lane = tid & 63;
  if (b < 50) {
    int idx = b * 4 + wave;                   // < 200, = tt*2+h
    int tt = idx >> 1, h = idx & 1;
    const float* pr = pos + (tt + 1) * DE;
    const float* qk = ws + WS_QK + h * DM + DE;
    float acc = 0.f;
    for (int j = lane; j < DE; j += 64) acc += pr[j] * qk[j];
    for (int o = 32; o; o >>= 1) acc += __shfl_xor(acc, o);
    if (!lane) ws[WS_CPOS + idx] = acc;
  } else if (b == 50) {
    if (wave < NH) {
      float acc = 0.f;
      for (int d = lane; d < DM; d += 64) acc += ws[WS_CLS + d] * ws[WS_QK + wave * DM + d];
      for (int o = 32; o; o >>= 1) acc += __shfl_xor(acc, o);
      if (!lane) ws[WS_S0 + wave] = acc;
    }
  } else {
    for (int n = tid; n < DM; n += 256) {
      float cs = 0.f, cv = bp1[n];
      for (int p = 0; p < 15; ++p) {
        cs += ws[WS_P3 + p * 600 + n];
        cv += ws[WS_P3 + p * 600 + 300 + n];
      }
      ws[WS_COLSUM + n] = cs;
      ws[WS_CVEC + n] = cv;
    }
  }
}

// ---------------- kA: fused h-GEMM -> scores -> softmax -> zbar -> msa ----------------
// 512 threads (8 waves); 2 blocks/CU -> 16 waves/CU.
// LDS: hb 30,400 + aux 5,120 + zb 2,400 = 37,920 B.
__launch_bounds__(512, 4)
__global__ void kA(const float* __restrict__ x, const float* __restrict__ Wp,
                   const float* __restrict__ bp, const float* __restrict__ pos,
                   const float* __restrict__ Wv, float* __restrict__ ws) {
  __shared__ __half hb[SS][DE + 2];
  __shared__ float aux[1280];
  __shared__ float zb[NH * DM];
  int b = blockIdx.x, tid = threadIdx.x;
  int tx = tid & 15, ty = tid >> 4;   // ty in [0,32)

  // ---- phase 1: h[b] = relu(x[b] @ Wp + bp) ----
  float acc[4][10];
#pragma unroll
  for (int i = 0; i < 4; ++i)
#pragma unroll
    for (int j = 0; j < 10; ++j) acc[i][j] = 0.f;
  const float* xb = x + b * SS * DM;
  int rows[4];
#pragma unroll
  for (int i = 0; i < 4; ++i) { int r = ty + 32 * i; rows[i] = (r < SS) ? r : (SS - 1); }

  for (int kc = 0; kc < 296; kc += 8) {
    for (int i = tid; i < 8 * 160; i += 512) {
      int kk = i / 160, c = i % 160;
      aux[i] = (c < DE) ? Wp[(kc + kk) * DE + c] : 0.f;
    }
    __syncthreads();
    float a[4][8];
#pragma unroll
    for (int i = 0; i < 4; ++i) {
      const float* xr = xb + rows[i] * DM + kc;
      float4 q0 = *(const float4*)xr;
      float4 q1 = *(const float4*)(xr + 4);
      a[i][0] = q0.x; a[i][1] = q0.y; a[i][2] = q0.z; a[i][3] = q0.w;
      a[i][4] = q1.x; a[i][5] = q1.y; a[i][6] = q1.z; a[i][7] = q1.w;
    }
#pragma unroll
    for (int kk = 0; kk < 8; ++kk) {
      float bv[10];
#pragma unroll
      for (int j = 0; j < 10; ++j) bv[j] = aux[kk * 160 + tx * 10 + j];
#pragma unroll
      for (int i = 0; i < 4; ++i)
#pragma unroll
        for (int j = 0; j < 10; ++j) acc[i][j] += a[i][kk] * bv[j];
    }
    __syncthreads();
  }
  { // tail: kc = 296, width 4
    const int kc = 296;
    for (int i = tid; i < 4 * 160; i += 512) {
      int kk = i / 160, c = i % 160;
      aux[i] = (c < DE) ? Wp[(kc + kk) * DE + c] : 0.f;
    }
    __syncthreads();
    float a[4][4];
#pragma unroll
    for (int i = 0; i < 4; ++i) {
      const float* xr = xb + rows[i] * DM + kc;
      float4 q0 = *(const float4*)xr;
      a[i][0] = q0.x; a[i][1] = q0.y; a[i][2] = q0.z; a[i][3] = q0.w;
    }
#pragma unroll
    for (int kk = 0; kk < 4; ++kk) {
      float bv[10];
#pragma unroll
      for (int j = 0; j < 10; ++j) bv[j] = aux[kk * 160 + tx * 10 + j];
#pragma unroll
      for (int i = 0; i < 4; ++i)
#pragma unroll
        for (int j = 0; j < 10; ++j) acc[i][j] += a[i][kk] * bv[j];
    }
    __syncthreads();
  }
#pragma unroll
  for (int i = 0; i < 4; ++i) {
    int r = ty + 32 * i;
    if (r < SS) {
#pragma unroll
      for (int j = 0; j < 10; ++j) {
        int c = tx * 10 + j;
        if (c < DE) {
          float v = acc[i][j] + bp[c];
          hb[r][c] = __float2half(v > 0.f ? v : 0.f);
        }
      }
    }
  }
  // reload aux: qk first-halves + cls
  for (int i = tid; i < DM; i += 512) {
    aux[i] = ws[WS_QK + (i / DE) * DM + (i % DE)];
    aux[DM + i] = ws[WS_CLS + i];
  }
  __syncthreads();

  // ---- phase 2: scores ----
  if (tid < NH * SS) {
    int hh = tid / SS, tt = tid % SS;
    float s = 0.f;
    for (int j = 0; j < DE; ++j) s += __half2float(hb[tt][j]) * aux[hh * DE + j];
    aux[600 + hh * LL + tt + 1] = s + ws[WS_CPOS + tt * NH + hh];
  } else if (tid < NH * SS + NH) {
    int hh = tid - NH * SS;
    aux[600 + hh * LL] = ws[WS_S0 + hh];
  }
  __syncthreads();

  // ---- phase 3: softmax (one wave per head) ----
  int wave = tid >> 6, lane = tid & 63;
  if (wave < NH) {
    float v0 = aux[600 + wave * LL + lane];
    float v1 = (lane + 64 < LL) ? aux[600 + wave * LL + lane + 64] : -1e30f;
    float m = fmaxf(v0, v1);
    for (int o = 32; o; o >>= 1) m = fmaxf(m, __shfl_xor(m, o));
    float e0 = expf(v0 - m);
    float e1 = (lane + 64 < LL) ? expf(v1 - m) : 0.f;
    float s = e0 + e1;
    for (int o = 32; o; o >>= 1) s += __shfl_xor(s, o);
    float inv = 1.f / s;
    aux[802 + wave * LL + lane] = e0 * inv;
    if (lane + 64 < LL) aux[802 + wave * LL + lane + 64] = e1 * inv;
  }
  __syncthreads();

  // ---- phase 4: zbar[h][d] = sum_t p[t]*z[b,t,d]  (into LDS) ----
  for (int o = tid; o < NH * DM; o += 512) {
    int hh = o / DM, d = o % DM;
    const float* p = &aux[802 + hh * LL];
    float acc2 = p[0] * aux[DM + d];
    if (d < DE) {
      for (int t = 1; t <= SS; ++t) acc2 += p[t] * __half2float(hb[t - 1][d]);
    } else {
      int dd = d - DE;
      for (int t = 1; t <= SS; ++t) acc2 += p[t] * pos[t * DE + dd];
    }
    zb[o] = acc2;
  }
  __syncthreads();

  // ---- phase 5: msa[b] = zb @ Wv (per head) ----
  for (int e = tid; e < NH * DM; e += 512) {
    int hh = e / DM, ee = e % DM;
    const float* wv = Wv + hh * DM * DM + ee;
    const float* z = zb + hh * DM;
    float s0 = 0.f, s1 = 0.f;
    for (int d = 0; d < DM; d += 2) {
      s0 += z[d] * wv[d * DM];
      s1 += z[d + 1] * wv[(d + 1) * DM];
    }
    ws[WS_MSA + b * 600 + e] = s0 + s1;
  }
}

// ---------------- k4a: bn1 channel-0 partial stats ----------------
__global__ void k4a(float* __restrict__ ws) {
  int tid = threadIdx.x, bid = blockIdx.x;
  float s = 0.f, ss = 0.f;
  for (int i = bid * 256 + tid; i < BB * 600; i += 64 * 256) {
    float v = ws[WS_MSA + i];
    s += v; ss += v * v;
  }
  for (int o = 32; o; o >>= 1) { s += __shfl_xor(s, o); ss += __shfl_xor(ss, o); }
  __shared__ float sh[2][4];
  int wave = tid >> 6, lane = tid & 63;
  if (!lane) { sh[0][wave] = s; sh[1][wave] = ss; }
  __syncthreads();
  if (!tid) {
    float S = 0.f, SS2 = 0.f;
    for (int w = 0; w < 4; ++w) { S += sh[0][w]; SS2 += sh[1][w]; }
    ws[WS_PART1 + bid * 2] = S;
    ws[WS_PART1 + bid * 2 + 1] = SS2;
  }
}

// ---------------- k5: bn1 finalize (inline) + y1 = relu(a1*(msa@Wp1[:600]) + ...) ----------------
__launch_bounds__(256)
__global__ void k5(const float* __restrict__ Wp1, const float* __restrict__ g1,
                   const float* __restrict__ b1, float* __restrict__ ws) {
  __shared__ float ab[2][600];
  __shared__ float s_a1, s_b1;
  int b0 = blockIdx.x * 2, tid = threadIdx.x;
  for (int i = tid; i < 2 * 600; i += 256) ab[i / 600][i % 600] = ws[WS_MSA + b0 * 600 + i];
  if (tid < 64) {
    float s = ws[WS_PART1 + tid * 2], ss = ws[WS_PART1 + tid * 2 + 1];
    for (int o = 32; o; o >>= 1) { s += __shfl_xor(s, o); ss += __shfl_xor(ss, o); }
    if (!tid) {
      float n = (float)(BB * 600);
      float mean = s / n, var = ss / n - mean * mean;
      float a = (1.f / sqrtf(var + 1e-5f)) * g1[0];
      s_a1 = a; s_b1 = b1[0] - a * mean;
      if (blockIdx.x == 0) { ws[WS_STATS + 0] = a; ws[WS_STATS + 1] = s_b1; }
    }
  }
  __syncthreads();
  float a1 = s_a1, beta1 = s_b1;
  for (int n = tid; n < DM; n += 256) {
    float acc0 = 0.f, acc1 = 0.f;
    for (int k = 0; k < 600; ++k) {
      float w = Wp1[k * 300 + n];
      acc0 += ab[0][k] * w;
      acc1 += ab[1][k] * w;
    }
    float c = beta1 * ws[WS_COLSUM + n] + ws[WS_CVEC + n];
    float v0 = a1 * acc0 + c, v1 = a1 * acc1 + c;
    ws[WS_Y1 + b0 * 300 + n] = v0 > 0.f ? v0 : 0.f;
    ws[WS_Y1 + (b0 + 1) * 300 + n] = v1 > 0.f ? v1 : 0.f;
  }
}

// ---------------- k6a: bn2 channel-0 partial stats ----------------
__global__ void k6a(float* __restrict__ ws) {
  int tid = threadIdx.x, bid = blockIdx.x;
  float s = 0.f, ss = 0.f;
  for (int i = bid * 256 + tid; i < BB * 300; i += 64 * 256) {
    float v = ws[WS_Y1 + i];
    s += v; ss += v * v;
  }
  for (int o = 32; o; o >>= 1) { s += __shfl_xor(s, o); ss += __shfl_xor(ss, o); }
  __shared__ float sh[2][4];
  int wave = tid >> 6, lane = tid & 63;
  if (!lane) { sh[0][wave] = s; sh[1][wave] = ss; }
  __syncthreads();
  if (!tid) {
    float S = 0.f, SS2 = 0.f;
    for (int w = 0; w < 4; ++w) { S += sh[0][w]; SS2 += sh[1][w]; }
    ws[WS_PART2 + bid * 2] = S;
    ws[WS_PART2 + bid * 2 + 1] = SS2;
  }
}

// ---------------- k7: bn2 finalize + consts (inline) + out ----------------
__global__ void k7(const float* __restrict__ g2, const float* __restrict__ b2,
                   float* __restrict__ out, const float* __restrict__ ws) {
  __shared__ float Gs[2400];
  __shared__ float sh[4];   // a2, b2s, c0, c1
  int tid = threadIdx.x;    // 64
  for (int i = tid; i < 2400; i += 64) Gs[i] = ws[WS_G + i];
  {
    float s = ws[WS_PART2 + tid * 2], ss = ws[WS_PART2 + tid * 2 + 1];
    for (int o = 32; o; o >>= 1) { s += __shfl_xor(s, o); ss += __shfl_xor(ss, o); }
    if (!tid) {
      float n = (float)(BB * 300);
      float mean = s / n, var = ss / n - mean * mean;
      float a = (1.f / sqrtf(var + 1e-5f)) * g2[0];
      sh[0] = a; sh[1] = b2[0] - a * mean;
    }
  }
  __syncthreads();
  if (tid < 2) {
    int c = tid;
    float sg1 = 0.f, sg2 = 0.f, sg3 = 0.f;
    for (int k = 0; k < 300; ++k) sg1 += Gs[k * 2 + c];
    for (int k = 300; k < 900; ++k) sg2 += Gs[k * 2 + c];
    for (int j = 0; j < 300; ++j) sg3 += ws[WS_CLS + j] * Gs[(900 + j) * 2 + c];
    sh[2 + c] = ws[WS_CST0 + c] + sg3 + sh[1] * sg1 + ws[WS_STATS + 1] * sg2;
  }
  __syncthreads();
  int b = blockIdx.x * 64 + tid;
  float a1 = ws[WS_STATS + 0], a2 = sh[0];
  float c0 = sh[2], c1 = sh[3];
  const float* y1 = ws + WS_Y1 + b * 300;
  const float* ms = ws + WS_MSA + b * 600;
  float o0 = 0.f, o1 = 0.f;
  for (int k = 0; k < 300; ++k) { float v = y1[k]; o0 += v * Gs[k * 2]; o1 += v * Gs[k * 2 + 1]; }
  float p0 = 0.f, p1 = 0.f;
  for (int j = 0; j < 600; ++j) { float v = ms[j]; p0 += v * Gs[(300 + j) * 2]; p1 += v * Gs[(300 + j) * 2 + 1]; }
  out[b * 2] = a2 * o0 + a1 * p0 + c0;
  out[b * 2 + 1] = a2 * o1 + a1 * p1 + c1;
}

extern "C" void kernel_launch(void* const* d_in, const int* in_sizes, int n_in,
                              void* d_out, int out_size, void* d_ws, size_t ws_size,
                              hipStream_t stream) {
  const float* x    = (const float*)d_in[0];
  const float* Wp   = (const float*)d_in[1];
  const float* bp   = (const float*)d_in[2];
  const float* pos  = (const float*)d_in[3];
  const float* cle  = (const float*)d_in[4];
  const float* Wq   = (const float*)d_in[5];
  const float* Wk   = (const float*)d_in[6];
  const float* Wv   = (const float*)d_in[7];
  const float* bn1g = (const float*)d_in[8];
  const float* bn1b = (const float*)d_in[9];
  const float* Wp1  = (const float*)d_in[10];
  const float* bp1  = (const float*)d_in[11];
  const float* bn2g = (const float*)d_in[12];
  const float* bn2b = (const float*)d_in[13];
  const float* f1W  = (const float*)d_in[14];
  const float* f1b  = (const float*)d_in[15];
  const float* f2W  = (const float*)d_in[16];
  const float* f2b  = (const float*)d_in[17];
  float* ws = (float*)d_ws;
  float* out = (float*)d_out;

  hipLaunchKernelGGL(kC1, dim3(29), dim3(256), 0, stream, pos, cle, Wq, Wp1, f1W, f2W, f1b, f2b, ws);
  hipLaunchKernelGGL(kC2, dim3(150), dim3(256), 0, stream, Wk, ws);
  hipLaunchKernelGGL(kC3, dim3(52), dim3(256), 0, stream, pos, bp1, ws);
  hipLaunchKernelGGL(kA, dim3(512), dim3(512), 0, stream, x, Wp, bp, pos, Wv, ws);
  hipLaunchKernelGGL(k4a, dim3(64), dim3(256), 0, stream, ws);
  hipLaunchKernelGGL(k5, dim3(256), dim3(256), 0, stream, Wp1, bn1g, bn1b, ws);
  hipLaunchKernelGGL(k6a, dim3(64), dim3(256), 0, stream, ws);
  hipLaunchKernelGGL(k7, dim3(8), dim3(64), 0, stream, bn2g, bn2b, out, ws);
}